// Round 11
// baseline (135.105 us; speedup 1.0000x reference)
//
#include <hip/hip_runtime.h>
#include <cstdint>
#include <cstddef>

// VmfVectorQuantizer round 11: R10 (4 waves per 16-row tile, 128 codes each,
// 16384 waves) with the divergent-wsum bug fixed: kd/kc wave reductions are
// computed BEFORE any divergent branch.

typedef __attribute__((ext_vector_type(8))) short short8;
typedef __attribute__((ext_vector_type(4))) float f32x4;

namespace {
constexpr float kEpsG = 1e-10f;
constexpr float kEpsN = 1e-12f;
constexpr float kEpsP = 1e-7f;
constexpr float kLog2e = 1.4426950408889634f;
constexpr float kLn2 = 0.6931471805599453f;
constexpr int kSlots = 128;
constexpr int kStride = 520;
}

__device__ __forceinline__ float wsum64(float v) {
#pragma unroll
    for (int m = 1; m < 64; m <<= 1) v += __shfl_xor(v, m, 64);
    return v;
}
__device__ __forceinline__ uint32_t pk_bf16(float a, float b) {
    uint32_t ua = __float_as_uint(a), ub = __float_as_uint(b);
    ua += 0x7fffu + ((ua >> 16) & 1u);
    ub += 0x7fffu + ((ub >> 16) & 1u);
    return (ua >> 16) | (ub & 0xffff0000u);
}
__device__ __forceinline__ uint16_t bf16_rne(float a) {
    uint32_t ua = __float_as_uint(a);
    ua += 0x7fffu + ((ua >> 16) & 1u);
    return (uint16_t)(ua >> 16);
}
__device__ __forceinline__ float dot4(float4 v) {
    return v.x * v.x + v.y * v.y + v.z * v.z + v.w * v.w;
}

__global__ __launch_bounds__(256) void k_prep(const float* __restrict__ cb,
                                              uint16_t* __restrict__ cbN,
                                              uint16_t* __restrict__ cbNT) {
    const int row = blockIdx.x * 4 + (threadIdx.x >> 6);
    const int lane = threadIdx.x & 63;
    const float v = cb[row * 64 + lane];
    const float ss = wsum64(v * v);
    const float nv = v / fmaxf(sqrtf(ss), kEpsN);
    const uint16_t h = bf16_rne(nv);
    cbN[row * 64 + lane] = h;
    cbNT[lane * 512 + row] = h;
}

// ---- k_main: 4 waves per 16-row tile; wave W owns codes [128W, 128W+128).
__global__ __launch_bounds__(256, 4) void k_main(
    const float* __restrict__ z, const float* __restrict__ kqp,
    const float* __restrict__ gum, const uint16_t* __restrict__ cbN,
    const uint16_t* __restrict__ cbNT, float* __restrict__ out,
    float* __restrict__ g_part) {
    __shared__ float avg_lds[512];
    __shared__ float cS[4][16], cW[4][16], cS2[4][16];
    __shared__ float4 accx[4][4][64];  // [src wave][dt][lane]

    const int tid = threadIdx.x;
    const int W = tid >> 6;
    const int l = tid & 63;
    const int g = l >> 4;
    const int rh = l & 15;
    const int r0 = blockIdx.x * 16;
    const int row = r0 + rh;
    const float kq = *kqp;

    // ---- z load + L2 normalize; fold kq*log2e into bf16 B-fragments
    const float* zr = z + (size_t)row * 64;
    const float4 a0 = *(const float4*)(zr + 8 * g);
    const float4 a1 = *(const float4*)(zr + 8 * g + 4);
    const float4 a2 = *(const float4*)(zr + 32 + 8 * g);
    const float4 a3 = *(const float4*)(zr + 36 + 8 * g);
    float ss = dot4(a0) + dot4(a1) + dot4(a2) + dot4(a3);
    ss += __shfl_xor(ss, 16, 64);
    ss += __shfl_xor(ss, 32, 64);
    const float scz = kq * kLog2e / fmaxf(sqrtf(ss), kEpsN);
    union U8 { short8 s; uint32_t u[4]; };
    U8 zb0, zb1;
    zb0.u[0] = pk_bf16(a0.x * scz, a0.y * scz);
    zb0.u[1] = pk_bf16(a0.z * scz, a0.w * scz);
    zb0.u[2] = pk_bf16(a1.x * scz, a1.y * scz);
    zb0.u[3] = pk_bf16(a1.z * scz, a1.w * scz);
    zb1.u[0] = pk_bf16(a2.x * scz, a2.y * scz);
    zb1.u[1] = pk_bf16(a2.z * scz, a2.w * scz);
    zb1.u[2] = pk_bf16(a3.x * scz, a3.y * scz);
    zb1.u[3] = pk_bf16(a3.z * scz, a3.w * scz);

    const float B1 = kq * kLog2e;  // static bound: x <= B1

    // ---- u tile 0 prefetch (hides under pass 1)
    const float* ur = gum + (size_t)row * 512 + 128 * W;
    float4 u0[4], u1[4];
#pragma unroll
    for (int j = 0; j < 4; ++j) u0[j] = *(const float4*)(ur + 16 * j + 4 * g);

    const uint16_t* cbW = cbN + (size_t)(128 * W) * 64;

    // ================= pass 1: logits -> e (bf16-packed), S, W ============
    uint32_t epk[16];
    float S4[4] = {0.f, 0.f, 0.f, 0.f}, W4[4] = {0.f, 0.f, 0.f, 0.f};
#pragma unroll
    for (int T = 0; T < 2; ++T) {
        short8 ca[8];
#pragma unroll
        for (int q = 0; q < 4; ++q) {
            const uint16_t* cr = cbW + (size_t)(64 * T + 16 * q + rh) * 64;
            ca[2 * q] = *(const short8*)(cr + 8 * g);
            ca[2 * q + 1] = *(const short8*)(cr + 32 + 8 * g);
        }
#pragma unroll
        for (int q = 0; q < 4; ++q) {
            f32x4 acc = {0.f, 0.f, 0.f, 0.f};
            acc = __builtin_amdgcn_mfma_f32_16x16x32_bf16(ca[2 * q], zb0.s, acc, 0, 0, 0);
            acc = __builtin_amdgcn_mfma_f32_16x16x32_bf16(ca[2 * q + 1], zb1.s, acc, 0, 0, 0);
            float e4[4];
#pragma unroll
            for (int i = 0; i < 4; ++i) {
                const float d = acc[i] - B1;
                const float e = __builtin_amdgcn_exp2f(d);
                e4[i] = e;
                S4[i] += e;
                W4[i] = fmaf(d, e, W4[i]);
            }
            epk[8 * T + 2 * q] = pk_bf16(e4[0], e4[1]);
            epk[8 * T + 2 * q + 1] = pk_bf16(e4[2], e4[3]);
        }
    }
    float Sr = (S4[0] + S4[1]) + (S4[2] + S4[3]);
    float Wr = (W4[0] + W4[1]) + (W4[2] + W4[3]);
    Sr += __shfl_xor(Sr, 16, 64);
    Sr += __shfl_xor(Sr, 32, 64);
    Wr += __shfl_xor(Wr, 16, 64);
    Wr += __shfl_xor(Wr, 32, 64);
    if (g == 0) { cS[W][rh] = Sr; cW[W][rh] = Wr; }
    // issue u tile 1 prefetch; latency overlaps the barrier wait
#pragma unroll
    for (int j = 0; j < 4; ++j)
        u1[j] = *(const float4*)(ur + 64 + 16 * j + 4 * g);
    __syncthreads();
    const float St = (cS[0][rh] + cS[1][rh]) + (cS[2][rh] + cS[3][rh]);
    const float Wt = (cW[0][rh] + cW[1][rh]) + (cW[2][rh] + cW[3][rh]);
    const float inv = 1.0f / St;
    const float kldd = kLn2 * (Wt * inv - __builtin_amdgcn_logf(St));

    // ================= pass 2: avg, rcp-gumbel, GEMM2 =====================
    float S24[4] = {0.f, 0.f, 0.f, 0.f};
    f32x4 acc2[4];
#pragma unroll
    for (int dt = 0; dt < 4; ++dt) acc2[dt] = (f32x4){0.f, 0.f, 0.f, 0.f};
    const int srcA = rh + 16 * ((2 * g) & 3);
    const int srcB = rh + 16 * ((2 * g + 1) & 3);
    const bool hi = (g & 2) != 0;

#pragma unroll
    for (int T = 0; T < 2; ++T) {
        // GEMM2 B loads first (L2-resident)
        short8 cb2[8];
#pragma unroll
        for (int dt = 0; dt < 4; ++dt)
#pragma unroll
            for (int ks = 0; ks < 2; ++ks)
                cb2[2 * dt + ks] = *(const short8*)(cbNT +
                    (size_t)(rh + 16 * dt) * 512 + 128 * W + 64 * T + 32 * ks + 8 * g);
        float4 uc[4];
#pragma unroll
        for (int j = 0; j < 4; ++j) uc[j] = (T == 0) ? u0[j] : u1[j];

        // unpack e (bf16 -> f32)
        float ev[16];
#pragma unroll
        for (int k2 = 0; k2 < 8; ++k2) {
            const uint32_t pe = epk[8 * T + k2];
            ev[2 * k2] = __uint_as_float(pe << 16);
            ev[2 * k2 + 1] = __uint_as_float(pe & 0xffff0000u);
        }

        // gumbel: e2 = (e * rcp(-ln(u+eps)+eps))^2; pack bf16 for GEMM2
        float pf[8];
#pragma unroll
        for (int q = 0; q < 4; ++q) {
            const float uu[4] = {uc[q].x, uc[q].y, uc[q].z, uc[q].w};
            float e2v[4];
#pragma unroll
            for (int i = 0; i < 4; ++i) {
                const float lg = __builtin_amdgcn_logf(uu[i] + kEpsG);
                const float inr = fmaf(lg, -kLn2, kEpsG);
                const float r = __builtin_amdgcn_rcpf(inr);
                const float t = ev[4 * q + i] * r;
                const float e2 = t * t;
                e2v[i] = e2;
                S24[i] += e2;
            }
            pf[2 * q] = __uint_as_float(pk_bf16(e2v[0], e2v[1]));
            pf[2 * q + 1] = __uint_as_float(pk_bf16(e2v[2], e2v[3]));
        }

        // p = e*inv; butterfly transpose-reduce over 16 rows (destroys ev)
#pragma unroll
        for (int j = 0; j < 16; ++j) ev[j] *= inv;
#pragma unroll
        for (int m = 1, nv = 8; m <= 8; m <<= 1, nv >>= 1) {
            const bool up_ = (rh & m) != 0;
#pragma unroll
            for (int t = 0; t < nv; ++t) {
                const float a = ev[t], b = ev[t + nv];
                const float keep = up_ ? b : a;
                const float send = up_ ? a : b;
                ev[t] = keep + __shfl_xor(send, m, 64);
            }
        }
        const int jr = ((rh & 1) << 3) | ((rh & 2) << 1) | ((rh & 4) >> 1) |
                       ((rh & 8) >> 3);
        avg_lds[128 * W + 64 * T + 16 * (jr >> 2) + 4 * g + (jr & 3)] = ev[0];

        // D->A exchange + GEMM2
#pragma unroll
        for (int ks = 0; ks < 2; ++ks) {
            const float a0lo = __shfl(pf[4 * ks + 0], srcA, 64);
            const float a1lo = __shfl(pf[4 * ks + 1], srcA, 64);
            const float a0hi = __shfl(pf[4 * ks + 2], srcA, 64);
            const float a1hi = __shfl(pf[4 * ks + 3], srcA, 64);
            const float b0lo = __shfl(pf[4 * ks + 0], srcB, 64);
            const float b1lo = __shfl(pf[4 * ks + 1], srcB, 64);
            const float b0hi = __shfl(pf[4 * ks + 2], srcB, 64);
            const float b1hi = __shfl(pf[4 * ks + 3], srcB, 64);
            U8 af;
            af.u[0] = __float_as_uint(hi ? a0hi : a0lo);
            af.u[1] = __float_as_uint(hi ? a1hi : a1lo);
            af.u[2] = __float_as_uint(hi ? b0hi : b0lo);
            af.u[3] = __float_as_uint(hi ? b1hi : b1lo);
#pragma unroll
            for (int dt = 0; dt < 4; ++dt)
                acc2[dt] = __builtin_amdgcn_mfma_f32_16x16x32_bf16(
                    af.s, cb2[2 * dt + ks], acc2[dt], 0, 0, 0);
        }
    }

    // ---- merge S2 + exchange acc2 partials (single barrier)
    float S2r = (S24[0] + S24[1]) + (S24[2] + S24[3]);
    S2r += __shfl_xor(S2r, 16, 64);
    S2r += __shfl_xor(S2r, 32, 64);
    if (g == 0) cS2[W][rh] = S2r;
#pragma unroll
    for (int dt = 0; dt < 4; ++dt)
        accx[W][dt][l] = make_float4(acc2[dt][0], acc2[dt][1], acc2[dt][2],
                                     acc2[dt][3]);
    __syncthreads();
    const float inv2 =
        1.0f / ((cS2[0][rh] + cS2[1][rh]) + (cS2[2][rh] + cS2[3][rh]));
    float ivi[4];
#pragma unroll
    for (int i = 0; i < 4; ++i) ivi[i] = __shfl(inv2, 4 * g + i, 64);

    // wave W owns dt = W: sum the 4 partials for its 16 d-columns
    f32x4 own = (W == 0) ? acc2[0] : (W == 1) ? acc2[1] : (W == 2) ? acc2[2]
                                                                   : acc2[3];
    float q4[4] = {0.f, 0.f, 0.f, 0.f};
#pragma unroll
    for (int w = 0; w < 4; ++w) {
        if (w == W) continue;
        const float4 xv = accx[w][W][l];
        q4[0] += xv.x;
        q4[1] += xv.y;
        q4[2] += xv.z;
        q4[3] += xv.w;
    }
    float kldc = 0.f;
#pragma unroll
    for (int i = 0; i < 4; ++i) {
        const float qv = (own[i] + q4[i]) * ivi[i];
        const size_t oi = (size_t)(r0 + 4 * g + i) * 64 + rh + 16 * W;
        out[oi] = qv;
        const float zv = z[oi];
        kldc = fmaf(zv, zv - qv, kldc);
    }

    // ---- scalar + avg reductions: wave reductions BEFORE any divergence
    const float kc = wsum64(kldc) * kq;
    const float kd = wsum64(kldd) * 0.25f;  // 4 g-lanes duplicate each row
    const int slot = blockIdx.x & (kSlots - 1);
    float* gp = g_part + (size_t)slot * kStride;
    if (l == 0) {
        atomicAdd(&gp[513], kc);
        if (W == 0) atomicAdd(&gp[512], kd);
    }
    // avg_lds fully written before the accx barrier
    if (W == 0) {
        const float4 av0 = *(const float4*)&avg_lds[l * 8];
        const float4 av1 = *(const float4*)&avg_lds[l * 8 + 4];
        atomicAdd(&gp[l * 8 + 0], av0.x);
        atomicAdd(&gp[l * 8 + 1], av0.y);
        atomicAdd(&gp[l * 8 + 2], av0.z);
        atomicAdd(&gp[l * 8 + 3], av0.w);
        atomicAdd(&gp[l * 8 + 4], av1.x);
        atomicAdd(&gp[l * 8 + 5], av1.y);
        atomicAdd(&gp[l * 8 + 6], av1.z);
        atomicAdd(&gp[l * 8 + 7], av1.w);
    }
}

__global__ __launch_bounds__(512) void k_final(const float* __restrict__ g_part,
                                               float* __restrict__ out) {
    __shared__ float red[8];
    const int tid = threadIdx.x;
    float sacc = 0.f;
#pragma unroll 8
    for (int i = 0; i < kSlots; ++i) sacc += g_part[(size_t)i * kStride + tid];
    const float avg = sacc * (1.0f / 65536.0f);
    const float t = avg * __logf(avg + kEpsP);
    const float sw = wsum64(t);
    if ((tid & 63) == 0) red[tid >> 6] = sw;
    __syncthreads();
    if (tid == 0) {
        float tot = 0.f;
#pragma unroll
        for (int i = 0; i < 8; ++i) tot += red[i];
        float sc0 = 0.f, sc1 = 0.f;
        for (int i = 0; i < kSlots; ++i) {
            sc0 += g_part[(size_t)i * kStride + 512];
            sc1 += g_part[(size_t)i * kStride + 513];
        }
        out[4194304] = (sc0 + sc1) * 0.125f;
        out[4194305] = __expf(-tot);
    }
}

extern "C" void kernel_launch(void* const* d_in, const int* in_sizes, int n_in,
                              void* d_out, int out_size, void* d_ws, size_t ws_size,
                              hipStream_t stream) {
    (void)in_sizes; (void)n_in; (void)out_size; (void)ws_size;
    const float* z   = (const float*)d_in[0];
    const float* kq  = (const float*)d_in[1];
    const float* cb  = (const float*)d_in[2];
    const float* gum = (const float*)d_in[3];
    float* out = (float*)d_out;

    uint16_t* cbN  = (uint16_t*)d_ws;
    uint16_t* cbNT = cbN + 32768;
    float* g_part  = (float*)(cbNT + 32768);

    (void)hipMemsetAsync(g_part, 0, kSlots * kStride * sizeof(float), stream);
    k_prep<<<128, 256, 0, stream>>>(cb, cbN, cbNT);
    k_main<<<4096, 256, 0, stream>>>(z, kq, gum, cbN, cbNT, out, g_part);
    k_final<<<1, 512, 0, stream>>>(g_part, out);
}

// Round 12
// 126.927 us; speedup vs baseline: 1.0644x; 1.0644x over previous
//
#include <hip/hip_runtime.h>
#include <cstdint>
#include <cstddef>

// VmfVectorQuantizer round 12: R11 (4 waves/16-row tile, 128 codes each)
// WITHOUT bulk codebook staging arrays (ca[8]/cb2[8] were 32 regs each ->
// spill at the 128-reg launch_bounds cap). Codebook loads move inside the
// MFMA loops; L2 latency hidden by 4-waves/SIMD TLP instead of staging.

typedef __attribute__((ext_vector_type(8))) short short8;
typedef __attribute__((ext_vector_type(4))) float f32x4;

namespace {
constexpr float kEpsG = 1e-10f;
constexpr float kEpsN = 1e-12f;
constexpr float kEpsP = 1e-7f;
constexpr float kLog2e = 1.4426950408889634f;
constexpr float kLn2 = 0.6931471805599453f;
constexpr int kSlots = 128;
constexpr int kStride = 520;
}

__device__ __forceinline__ float wsum64(float v) {
#pragma unroll
    for (int m = 1; m < 64; m <<= 1) v += __shfl_xor(v, m, 64);
    return v;
}
__device__ __forceinline__ uint32_t pk_bf16(float a, float b) {
    uint32_t ua = __float_as_uint(a), ub = __float_as_uint(b);
    ua += 0x7fffu + ((ua >> 16) & 1u);
    ub += 0x7fffu + ((ub >> 16) & 1u);
    return (ua >> 16) | (ub & 0xffff0000u);
}
__device__ __forceinline__ uint16_t bf16_rne(float a) {
    uint32_t ua = __float_as_uint(a);
    ua += 0x7fffu + ((ua >> 16) & 1u);
    return (uint16_t)(ua >> 16);
}
__device__ __forceinline__ float dot4(float4 v) {
    return v.x * v.x + v.y * v.y + v.z * v.z + v.w * v.w;
}

__global__ __launch_bounds__(256) void k_prep(const float* __restrict__ cb,
                                              uint16_t* __restrict__ cbN,
                                              uint16_t* __restrict__ cbNT) {
    const int row = blockIdx.x * 4 + (threadIdx.x >> 6);
    const int lane = threadIdx.x & 63;
    const float v = cb[row * 64 + lane];
    const float ss = wsum64(v * v);
    const float nv = v / fmaxf(sqrtf(ss), kEpsN);
    const uint16_t h = bf16_rne(nv);
    cbN[row * 64 + lane] = h;
    cbNT[lane * 512 + row] = h;
}

// ---- k_main: 4 waves per 16-row tile; wave W owns codes [128W, 128W+128).
__global__ __launch_bounds__(256, 4) void k_main(
    const float* __restrict__ z, const float* __restrict__ kqp,
    const float* __restrict__ gum, const uint16_t* __restrict__ cbN,
    const uint16_t* __restrict__ cbNT, float* __restrict__ out,
    float* __restrict__ g_part) {
    __shared__ float avg_lds[512];
    __shared__ float cS[4][16], cW[4][16], cS2[4][16];
    __shared__ float4 accx[4][4][64];  // [src wave][dt][lane]

    const int tid = threadIdx.x;
    const int W = tid >> 6;
    const int l = tid & 63;
    const int g = l >> 4;
    const int rh = l & 15;
    const int r0 = blockIdx.x * 16;
    const int row = r0 + rh;
    const float kq = *kqp;

    // ---- z load + L2 normalize; fold kq*log2e into bf16 B-fragments
    const float* zr = z + (size_t)row * 64;
    const float4 a0 = *(const float4*)(zr + 8 * g);
    const float4 a1 = *(const float4*)(zr + 8 * g + 4);
    const float4 a2 = *(const float4*)(zr + 32 + 8 * g);
    const float4 a3 = *(const float4*)(zr + 36 + 8 * g);
    float ss = dot4(a0) + dot4(a1) + dot4(a2) + dot4(a3);
    ss += __shfl_xor(ss, 16, 64);
    ss += __shfl_xor(ss, 32, 64);
    const float scz = kq * kLog2e / fmaxf(sqrtf(ss), kEpsN);
    union U8 { short8 s; uint32_t u[4]; };
    U8 zb0, zb1;
    zb0.u[0] = pk_bf16(a0.x * scz, a0.y * scz);
    zb0.u[1] = pk_bf16(a0.z * scz, a0.w * scz);
    zb0.u[2] = pk_bf16(a1.x * scz, a1.y * scz);
    zb0.u[3] = pk_bf16(a1.z * scz, a1.w * scz);
    zb1.u[0] = pk_bf16(a2.x * scz, a2.y * scz);
    zb1.u[1] = pk_bf16(a2.z * scz, a2.w * scz);
    zb1.u[2] = pk_bf16(a3.x * scz, a3.y * scz);
    zb1.u[3] = pk_bf16(a3.z * scz, a3.w * scz);

    const float B1 = kq * kLog2e;  // static bound: x <= B1

    // ---- u tile 0 prefetch (hides under pass 1)
    const float* ur = gum + (size_t)row * 512 + 128 * W;
    float4 u0[4], u1[4];
#pragma unroll
    for (int j = 0; j < 4; ++j) u0[j] = *(const float4*)(ur + 16 * j + 4 * g);

    const uint16_t* cbW = cbN + (size_t)(128 * W) * 64;

    // ================= pass 1: logits -> e (bf16-packed), S, W ============
    uint32_t epk[16];
    float S4[4] = {0.f, 0.f, 0.f, 0.f}, W4[4] = {0.f, 0.f, 0.f, 0.f};
#pragma unroll
    for (int T = 0; T < 2; ++T) {
#pragma unroll
        for (int q = 0; q < 4; ++q) {
            const uint16_t* cr = cbW + (size_t)(64 * T + 16 * q + rh) * 64;
            const short8 ca0 = *(const short8*)(cr + 8 * g);
            const short8 ca1 = *(const short8*)(cr + 32 + 8 * g);
            f32x4 acc = {0.f, 0.f, 0.f, 0.f};
            acc = __builtin_amdgcn_mfma_f32_16x16x32_bf16(ca0, zb0.s, acc, 0, 0, 0);
            acc = __builtin_amdgcn_mfma_f32_16x16x32_bf16(ca1, zb1.s, acc, 0, 0, 0);
            float e4[4];
#pragma unroll
            for (int i = 0; i < 4; ++i) {
                const float d = acc[i] - B1;
                const float e = __builtin_amdgcn_exp2f(d);
                e4[i] = e;
                S4[i] += e;
                W4[i] = fmaf(d, e, W4[i]);
            }
            epk[8 * T + 2 * q] = pk_bf16(e4[0], e4[1]);
            epk[8 * T + 2 * q + 1] = pk_bf16(e4[2], e4[3]);
        }
    }
    float Sr = (S4[0] + S4[1]) + (S4[2] + S4[3]);
    float Wr = (W4[0] + W4[1]) + (W4[2] + W4[3]);
    Sr += __shfl_xor(Sr, 16, 64);
    Sr += __shfl_xor(Sr, 32, 64);
    Wr += __shfl_xor(Wr, 16, 64);
    Wr += __shfl_xor(Wr, 32, 64);
    if (g == 0) { cS[W][rh] = Sr; cW[W][rh] = Wr; }
    // issue u tile 1 prefetch; latency overlaps the barrier wait
#pragma unroll
    for (int j = 0; j < 4; ++j)
        u1[j] = *(const float4*)(ur + 64 + 16 * j + 4 * g);
    __syncthreads();
    const float St = (cS[0][rh] + cS[1][rh]) + (cS[2][rh] + cS[3][rh]);
    const float Wt = (cW[0][rh] + cW[1][rh]) + (cW[2][rh] + cW[3][rh]);
    const float inv = 1.0f / St;
    const float kldd = kLn2 * (Wt * inv - __builtin_amdgcn_logf(St));

    // ================= pass 2: avg, rcp-gumbel, GEMM2 =====================
    float S24[4] = {0.f, 0.f, 0.f, 0.f};
    f32x4 acc2[4];
#pragma unroll
    for (int dt = 0; dt < 4; ++dt) acc2[dt] = (f32x4){0.f, 0.f, 0.f, 0.f};
    const int srcA = rh + 16 * ((2 * g) & 3);
    const int srcB = rh + 16 * ((2 * g + 1) & 3);
    const bool hi = (g & 2) != 0;

#pragma unroll
    for (int T = 0; T < 2; ++T) {
        float4 uc[4];
#pragma unroll
        for (int j = 0; j < 4; ++j) uc[j] = (T == 0) ? u0[j] : u1[j];

        // unpack e (bf16 -> f32)
        float ev[16];
#pragma unroll
        for (int k2 = 0; k2 < 8; ++k2) {
            const uint32_t pe = epk[8 * T + k2];
            ev[2 * k2] = __uint_as_float(pe << 16);
            ev[2 * k2 + 1] = __uint_as_float(pe & 0xffff0000u);
        }

        // gumbel: e2 = (e * rcp(-ln(u+eps)+eps))^2; pack bf16 for GEMM2
        float pf[8];
#pragma unroll
        for (int q = 0; q < 4; ++q) {
            const float uu[4] = {uc[q].x, uc[q].y, uc[q].z, uc[q].w};
            float e2v[4];
#pragma unroll
            for (int i = 0; i < 4; ++i) {
                const float lg = __builtin_amdgcn_logf(uu[i] + kEpsG);
                const float inr = fmaf(lg, -kLn2, kEpsG);
                const float r = __builtin_amdgcn_rcpf(inr);
                const float t = ev[4 * q + i] * r;
                const float e2 = t * t;
                e2v[i] = e2;
                S24[i] += e2;
            }
            pf[2 * q] = __uint_as_float(pk_bf16(e2v[0], e2v[1]));
            pf[2 * q + 1] = __uint_as_float(pk_bf16(e2v[2], e2v[3]));
        }

        // p = e*inv; butterfly transpose-reduce over 16 rows (destroys ev)
#pragma unroll
        for (int j = 0; j < 16; ++j) ev[j] *= inv;
#pragma unroll
        for (int m = 1, nv = 8; m <= 8; m <<= 1, nv >>= 1) {
            const bool up_ = (rh & m) != 0;
#pragma unroll
            for (int t = 0; t < nv; ++t) {
                const float a = ev[t], b = ev[t + nv];
                const float keep = up_ ? b : a;
                const float send = up_ ? a : b;
                ev[t] = keep + __shfl_xor(send, m, 64);
            }
        }
        const int jr = ((rh & 1) << 3) | ((rh & 2) << 1) | ((rh & 4) >> 1) |
                       ((rh & 8) >> 3);
        avg_lds[128 * W + 64 * T + 16 * (jr >> 2) + 4 * g + (jr & 3)] = ev[0];

        // D->A exchange + GEMM2 (codebook loaded inside, no staging array)
#pragma unroll
        for (int ks = 0; ks < 2; ++ks) {
            const float a0lo = __shfl(pf[4 * ks + 0], srcA, 64);
            const float a1lo = __shfl(pf[4 * ks + 1], srcA, 64);
            const float a0hi = __shfl(pf[4 * ks + 2], srcA, 64);
            const float a1hi = __shfl(pf[4 * ks + 3], srcA, 64);
            const float b0lo = __shfl(pf[4 * ks + 0], srcB, 64);
            const float b1lo = __shfl(pf[4 * ks + 1], srcB, 64);
            const float b0hi = __shfl(pf[4 * ks + 2], srcB, 64);
            const float b1hi = __shfl(pf[4 * ks + 3], srcB, 64);
            U8 af;
            af.u[0] = __float_as_uint(hi ? a0hi : a0lo);
            af.u[1] = __float_as_uint(hi ? a1hi : a1lo);
            af.u[2] = __float_as_uint(hi ? b0hi : b0lo);
            af.u[3] = __float_as_uint(hi ? b1hi : b1lo);
#pragma unroll
            for (int dt = 0; dt < 4; ++dt) {
                const short8 bf = *(const short8*)(cbNT +
                    (size_t)(rh + 16 * dt) * 512 + 128 * W + 64 * T + 32 * ks + 8 * g);
                acc2[dt] = __builtin_amdgcn_mfma_f32_16x16x32_bf16(
                    af.s, bf, acc2[dt], 0, 0, 0);
            }
        }
    }

    // ---- merge S2 + exchange acc2 partials (single barrier)
    float S2r = (S24[0] + S24[1]) + (S24[2] + S24[3]);
    S2r += __shfl_xor(S2r, 16, 64);
    S2r += __shfl_xor(S2r, 32, 64);
    if (g == 0) cS2[W][rh] = S2r;
#pragma unroll
    for (int dt = 0; dt < 4; ++dt)
        accx[W][dt][l] = make_float4(acc2[dt][0], acc2[dt][1], acc2[dt][2],
                                     acc2[dt][3]);
    __syncthreads();
    const float inv2 =
        1.0f / ((cS2[0][rh] + cS2[1][rh]) + (cS2[2][rh] + cS2[3][rh]));
    float ivi[4];
#pragma unroll
    for (int i = 0; i < 4; ++i) ivi[i] = __shfl(inv2, 4 * g + i, 64);

    // wave W owns dt = W: sum the 4 partials for its 16 d-columns
    f32x4 own = (W == 0) ? acc2[0] : (W == 1) ? acc2[1] : (W == 2) ? acc2[2]
                                                                   : acc2[3];
    float q4[4] = {0.f, 0.f, 0.f, 0.f};
#pragma unroll
    for (int w = 0; w < 4; ++w) {
        if (w == W) continue;
        const float4 xv = accx[w][W][l];
        q4[0] += xv.x;
        q4[1] += xv.y;
        q4[2] += xv.z;
        q4[3] += xv.w;
    }
    float kldc = 0.f;
#pragma unroll
    for (int i = 0; i < 4; ++i) {
        const float qv = (own[i] + q4[i]) * ivi[i];
        const size_t oi = (size_t)(r0 + 4 * g + i) * 64 + rh + 16 * W;
        out[oi] = qv;
        const float zv = z[oi];
        kldc = fmaf(zv, zv - qv, kldc);
    }

    // ---- scalar + avg reductions: wave reductions BEFORE any divergence
    const float kc = wsum64(kldc) * kq;
    const float kd = wsum64(kldd) * 0.25f;  // 4 g-lanes duplicate each row
    const int slot = blockIdx.x & (kSlots - 1);
    float* gp = g_part + (size_t)slot * kStride;
    if (l == 0) {
        atomicAdd(&gp[513], kc);
        if (W == 0) atomicAdd(&gp[512], kd);
    }
    // avg_lds fully written before the accx barrier
    if (W == 0) {
        const float4 av0 = *(const float4*)&avg_lds[l * 8];
        const float4 av1 = *(const float4*)&avg_lds[l * 8 + 4];
        atomicAdd(&gp[l * 8 + 0], av0.x);
        atomicAdd(&gp[l * 8 + 1], av0.y);
        atomicAdd(&gp[l * 8 + 2], av0.z);
        atomicAdd(&gp[l * 8 + 3], av0.w);
        atomicAdd(&gp[l * 8 + 4], av1.x);
        atomicAdd(&gp[l * 8 + 5], av1.y);
        atomicAdd(&gp[l * 8 + 6], av1.z);
        atomicAdd(&gp[l * 8 + 7], av1.w);
    }
}

__global__ __launch_bounds__(512) void k_final(const float* __restrict__ g_part,
                                               float* __restrict__ out) {
    __shared__ float red[8];
    const int tid = threadIdx.x;
    float sacc = 0.f;
#pragma unroll 8
    for (int i = 0; i < kSlots; ++i) sacc += g_part[(size_t)i * kStride + tid];
    const float avg = sacc * (1.0f / 65536.0f);
    const float t = avg * __logf(avg + kEpsP);
    const float sw = wsum64(t);
    if ((tid & 63) == 0) red[tid >> 6] = sw;
    __syncthreads();
    if (tid == 0) {
        float tot = 0.f;
#pragma unroll
        for (int i = 0; i < 8; ++i) tot += red[i];
        float sc0 = 0.f, sc1 = 0.f;
        for (int i = 0; i < kSlots; ++i) {
            sc0 += g_part[(size_t)i * kStride + 512];
            sc1 += g_part[(size_t)i * kStride + 513];
        }
        out[4194304] = (sc0 + sc1) * 0.125f;
        out[4194305] = __expf(-tot);
    }
}

extern "C" void kernel_launch(void* const* d_in, const int* in_sizes, int n_in,
                              void* d_out, int out_size, void* d_ws, size_t ws_size,
                              hipStream_t stream) {
    (void)in_sizes; (void)n_in; (void)out_size; (void)ws_size;
    const float* z   = (const float*)d_in[0];
    const float* kq  = (const float*)d_in[1];
    const float* cb  = (const float*)d_in[2];
    const float* gum = (const float*)d_in[3];
    float* out = (float*)d_out;

    uint16_t* cbN  = (uint16_t*)d_ws;
    uint16_t* cbNT = cbN + 32768;
    float* g_part  = (float*)(cbNT + 32768);

    (void)hipMemsetAsync(g_part, 0, kSlots * kStride * sizeof(float), stream);
    k_prep<<<128, 256, 0, stream>>>(cb, cbN, cbNT);
    k_main<<<4096, 256, 0, stream>>>(z, kq, gum, cbN, cbNT, out, g_part);
    k_final<<<1, 512, 0, stream>>>(g_part, out);
}

// Round 13
// 125.005 us; speedup vs baseline: 1.0808x; 1.0154x over previous
//
#include <hip/hip_runtime.h>
#include <cstdint>
#include <cstddef>

// VmfVectorQuantizer round 13: R12 with launch_bounds(256,3) — 170-reg
// budget fits the ~120-reg live set with ZERO spill (R12's (256,4)=128-reg
// cap spilled ~60 MB of scratch per dispatch and stalled every chain).
// 4 waves per 16-row tile, 128 codes/wave, 16384 waves.

typedef __attribute__((ext_vector_type(8))) short short8;
typedef __attribute__((ext_vector_type(4))) float f32x4;

namespace {
constexpr float kEpsG = 1e-10f;
constexpr float kEpsN = 1e-12f;
constexpr float kEpsP = 1e-7f;
constexpr float kLog2e = 1.4426950408889634f;
constexpr float kLn2 = 0.6931471805599453f;
constexpr int kSlots = 128;
constexpr int kStride = 520;
}

__device__ __forceinline__ float wsum64(float v) {
#pragma unroll
    for (int m = 1; m < 64; m <<= 1) v += __shfl_xor(v, m, 64);
    return v;
}
__device__ __forceinline__ uint32_t pk_bf16(float a, float b) {
    uint32_t ua = __float_as_uint(a), ub = __float_as_uint(b);
    ua += 0x7fffu + ((ua >> 16) & 1u);
    ub += 0x7fffu + ((ub >> 16) & 1u);
    return (ua >> 16) | (ub & 0xffff0000u);
}
__device__ __forceinline__ uint16_t bf16_rne(float a) {
    uint32_t ua = __float_as_uint(a);
    ua += 0x7fffu + ((ua >> 16) & 1u);
    return (uint16_t)(ua >> 16);
}
__device__ __forceinline__ float dot4(float4 v) {
    return v.x * v.x + v.y * v.y + v.z * v.z + v.w * v.w;
}

__global__ __launch_bounds__(256) void k_prep(const float* __restrict__ cb,
                                              uint16_t* __restrict__ cbN,
                                              uint16_t* __restrict__ cbNT) {
    const int row = blockIdx.x * 4 + (threadIdx.x >> 6);
    const int lane = threadIdx.x & 63;
    const float v = cb[row * 64 + lane];
    const float ss = wsum64(v * v);
    const float nv = v / fmaxf(sqrtf(ss), kEpsN);
    const uint16_t h = bf16_rne(nv);
    cbN[row * 64 + lane] = h;
    cbNT[lane * 512 + row] = h;
}

// ---- k_main: 4 waves per 16-row tile; wave W owns codes [128W, 128W+128).
__global__ __launch_bounds__(256, 3) void k_main(
    const float* __restrict__ z, const float* __restrict__ kqp,
    const float* __restrict__ gum, const uint16_t* __restrict__ cbN,
    const uint16_t* __restrict__ cbNT, float* __restrict__ out,
    float* __restrict__ g_part) {
    __shared__ float avg_lds[512];
    __shared__ float cS[4][16], cW[4][16], cS2[4][16];
    __shared__ float4 accx[4][4][64];  // [src wave][dt][lane]

    const int tid = threadIdx.x;
    const int W = tid >> 6;
    const int l = tid & 63;
    const int g = l >> 4;
    const int rh = l & 15;
    const int r0 = blockIdx.x * 16;
    const int row = r0 + rh;
    const float kq = *kqp;

    // ---- z load + L2 normalize; fold kq*log2e into bf16 B-fragments
    const float* zr = z + (size_t)row * 64;
    const float4 a0 = *(const float4*)(zr + 8 * g);
    const float4 a1 = *(const float4*)(zr + 8 * g + 4);
    const float4 a2 = *(const float4*)(zr + 32 + 8 * g);
    const float4 a3 = *(const float4*)(zr + 36 + 8 * g);
    float ss = dot4(a0) + dot4(a1) + dot4(a2) + dot4(a3);
    ss += __shfl_xor(ss, 16, 64);
    ss += __shfl_xor(ss, 32, 64);
    const float scz = kq * kLog2e / fmaxf(sqrtf(ss), kEpsN);
    union U8 { short8 s; uint32_t u[4]; };
    U8 zb0, zb1;
    zb0.u[0] = pk_bf16(a0.x * scz, a0.y * scz);
    zb0.u[1] = pk_bf16(a0.z * scz, a0.w * scz);
    zb0.u[2] = pk_bf16(a1.x * scz, a1.y * scz);
    zb0.u[3] = pk_bf16(a1.z * scz, a1.w * scz);
    zb1.u[0] = pk_bf16(a2.x * scz, a2.y * scz);
    zb1.u[1] = pk_bf16(a2.z * scz, a2.w * scz);
    zb1.u[2] = pk_bf16(a3.x * scz, a3.y * scz);
    zb1.u[3] = pk_bf16(a3.z * scz, a3.w * scz);

    const float B1 = kq * kLog2e;  // static bound: x <= B1

    // ---- u tile 0 prefetch (hides under pass 1)
    const float* ur = gum + (size_t)row * 512 + 128 * W;
    float4 u0[4], u1[4];
#pragma unroll
    for (int j = 0; j < 4; ++j) u0[j] = *(const float4*)(ur + 16 * j + 4 * g);

    const uint16_t* cbW = cbN + (size_t)(128 * W) * 64;

    // ================= pass 1: logits -> e (bf16-packed), S, W ============
    uint32_t epk[16];
    float S4[4] = {0.f, 0.f, 0.f, 0.f}, W4[4] = {0.f, 0.f, 0.f, 0.f};
#pragma unroll
    for (int T = 0; T < 2; ++T) {
#pragma unroll
        for (int q = 0; q < 4; ++q) {
            const uint16_t* cr = cbW + (size_t)(64 * T + 16 * q + rh) * 64;
            const short8 ca0 = *(const short8*)(cr + 8 * g);
            const short8 ca1 = *(const short8*)(cr + 32 + 8 * g);
            f32x4 acc = {0.f, 0.f, 0.f, 0.f};
            acc = __builtin_amdgcn_mfma_f32_16x16x32_bf16(ca0, zb0.s, acc, 0, 0, 0);
            acc = __builtin_amdgcn_mfma_f32_16x16x32_bf16(ca1, zb1.s, acc, 0, 0, 0);
            float e4[4];
#pragma unroll
            for (int i = 0; i < 4; ++i) {
                const float d = acc[i] - B1;
                const float e = __builtin_amdgcn_exp2f(d);
                e4[i] = e;
                S4[i] += e;
                W4[i] = fmaf(d, e, W4[i]);
            }
            epk[8 * T + 2 * q] = pk_bf16(e4[0], e4[1]);
            epk[8 * T + 2 * q + 1] = pk_bf16(e4[2], e4[3]);
        }
    }
    float Sr = (S4[0] + S4[1]) + (S4[2] + S4[3]);
    float Wr = (W4[0] + W4[1]) + (W4[2] + W4[3]);
    Sr += __shfl_xor(Sr, 16, 64);
    Sr += __shfl_xor(Sr, 32, 64);
    Wr += __shfl_xor(Wr, 16, 64);
    Wr += __shfl_xor(Wr, 32, 64);
    if (g == 0) { cS[W][rh] = Sr; cW[W][rh] = Wr; }
    // issue u tile 1 prefetch; latency overlaps the barrier wait
#pragma unroll
    for (int j = 0; j < 4; ++j)
        u1[j] = *(const float4*)(ur + 64 + 16 * j + 4 * g);
    __syncthreads();
    const float St = (cS[0][rh] + cS[1][rh]) + (cS[2][rh] + cS[3][rh]);
    const float Wt = (cW[0][rh] + cW[1][rh]) + (cW[2][rh] + cW[3][rh]);
    const float inv = 1.0f / St;
    const float kldd = kLn2 * (Wt * inv - __builtin_amdgcn_logf(St));

    // ================= pass 2: avg, rcp-gumbel, GEMM2 =====================
    float S24[4] = {0.f, 0.f, 0.f, 0.f};
    f32x4 acc2[4];
#pragma unroll
    for (int dt = 0; dt < 4; ++dt) acc2[dt] = (f32x4){0.f, 0.f, 0.f, 0.f};
    const int srcA = rh + 16 * ((2 * g) & 3);
    const int srcB = rh + 16 * ((2 * g + 1) & 3);
    const bool hi = (g & 2) != 0;

#pragma unroll
    for (int T = 0; T < 2; ++T) {
        float4 uc[4];
#pragma unroll
        for (int j = 0; j < 4; ++j) uc[j] = (T == 0) ? u0[j] : u1[j];

        // unpack e (bf16 -> f32)
        float ev[16];
#pragma unroll
        for (int k2 = 0; k2 < 8; ++k2) {
            const uint32_t pe = epk[8 * T + k2];
            ev[2 * k2] = __uint_as_float(pe << 16);
            ev[2 * k2 + 1] = __uint_as_float(pe & 0xffff0000u);
        }

        // gumbel: e2 = (e * rcp(-ln(u+eps)+eps))^2; pack bf16 for GEMM2
        float pf[8];
#pragma unroll
        for (int q = 0; q < 4; ++q) {
            const float uu[4] = {uc[q].x, uc[q].y, uc[q].z, uc[q].w};
            float e2v[4];
#pragma unroll
            for (int i = 0; i < 4; ++i) {
                const float lg = __builtin_amdgcn_logf(uu[i] + kEpsG);
                const float inr = fmaf(lg, -kLn2, kEpsG);
                const float r = __builtin_amdgcn_rcpf(inr);
                const float t = ev[4 * q + i] * r;
                const float e2 = t * t;
                e2v[i] = e2;
                S24[i] += e2;
            }
            pf[2 * q] = __uint_as_float(pk_bf16(e2v[0], e2v[1]));
            pf[2 * q + 1] = __uint_as_float(pk_bf16(e2v[2], e2v[3]));
        }

        // p = e*inv; butterfly transpose-reduce over 16 rows (destroys ev)
#pragma unroll
        for (int j = 0; j < 16; ++j) ev[j] *= inv;
#pragma unroll
        for (int m = 1, nv = 8; m <= 8; m <<= 1, nv >>= 1) {
            const bool up_ = (rh & m) != 0;
#pragma unroll
            for (int t = 0; t < nv; ++t) {
                const float a = ev[t], b = ev[t + nv];
                const float keep = up_ ? b : a;
                const float send = up_ ? a : b;
                ev[t] = keep + __shfl_xor(send, m, 64);
            }
        }
        const int jr = ((rh & 1) << 3) | ((rh & 2) << 1) | ((rh & 4) >> 1) |
                       ((rh & 8) >> 3);
        avg_lds[128 * W + 64 * T + 16 * (jr >> 2) + 4 * g + (jr & 3)] = ev[0];

        // D->A exchange + GEMM2 (codebook loaded inside, no staging array)
#pragma unroll
        for (int ks = 0; ks < 2; ++ks) {
            const float a0lo = __shfl(pf[4 * ks + 0], srcA, 64);
            const float a1lo = __shfl(pf[4 * ks + 1], srcA, 64);
            const float a0hi = __shfl(pf[4 * ks + 2], srcA, 64);
            const float a1hi = __shfl(pf[4 * ks + 3], srcA, 64);
            const float b0lo = __shfl(pf[4 * ks + 0], srcB, 64);
            const float b1lo = __shfl(pf[4 * ks + 1], srcB, 64);
            const float b0hi = __shfl(pf[4 * ks + 2], srcB, 64);
            const float b1hi = __shfl(pf[4 * ks + 3], srcB, 64);
            U8 af;
            af.u[0] = __float_as_uint(hi ? a0hi : a0lo);
            af.u[1] = __float_as_uint(hi ? a1hi : a1lo);
            af.u[2] = __float_as_uint(hi ? b0hi : b0lo);
            af.u[3] = __float_as_uint(hi ? b1hi : b1lo);
#pragma unroll
            for (int dt = 0; dt < 4; ++dt) {
                const short8 bf = *(const short8*)(cbNT +
                    (size_t)(rh + 16 * dt) * 512 + 128 * W + 64 * T + 32 * ks + 8 * g);
                acc2[dt] = __builtin_amdgcn_mfma_f32_16x16x32_bf16(
                    af.s, bf, acc2[dt], 0, 0, 0);
            }
        }
    }

    // ---- merge S2 + exchange acc2 partials (single barrier)
    float S2r = (S24[0] + S24[1]) + (S24[2] + S24[3]);
    S2r += __shfl_xor(S2r, 16, 64);
    S2r += __shfl_xor(S2r, 32, 64);
    if (g == 0) cS2[W][rh] = S2r;
#pragma unroll
    for (int dt = 0; dt < 4; ++dt)
        accx[W][dt][l] = make_float4(acc2[dt][0], acc2[dt][1], acc2[dt][2],
                                     acc2[dt][3]);
    __syncthreads();
    const float inv2 =
        1.0f / ((cS2[0][rh] + cS2[1][rh]) + (cS2[2][rh] + cS2[3][rh]));
    float ivi[4];
#pragma unroll
    for (int i = 0; i < 4; ++i) ivi[i] = __shfl(inv2, 4 * g + i, 64);

    // wave W owns dt = W: sum the 4 partials for its 16 d-columns
    f32x4 own = (W == 0) ? acc2[0] : (W == 1) ? acc2[1] : (W == 2) ? acc2[2]
                                                                   : acc2[3];
    float q4[4] = {0.f, 0.f, 0.f, 0.f};
#pragma unroll
    for (int w = 0; w < 4; ++w) {
        if (w == W) continue;
        const float4 xv = accx[w][W][l];
        q4[0] += xv.x;
        q4[1] += xv.y;
        q4[2] += xv.z;
        q4[3] += xv.w;
    }
    float kldc = 0.f;
#pragma unroll
    for (int i = 0; i < 4; ++i) {
        const float qv = (own[i] + q4[i]) * ivi[i];
        const size_t oi = (size_t)(r0 + 4 * g + i) * 64 + rh + 16 * W;
        out[oi] = qv;
        const float zv = z[oi];
        kldc = fmaf(zv, zv - qv, kldc);
    }

    // ---- scalar + avg reductions: wave reductions BEFORE any divergence
    const float kc = wsum64(kldc) * kq;
    const float kd = wsum64(kldd) * 0.25f;  // 4 g-lanes duplicate each row
    const int slot = blockIdx.x & (kSlots - 1);
    float* gp = g_part + (size_t)slot * kStride;
    if (l == 0) {
        atomicAdd(&gp[513], kc);
        if (W == 0) atomicAdd(&gp[512], kd);
    }
    // avg_lds fully written before the accx barrier
    if (W == 0) {
        const float4 av0 = *(const float4*)&avg_lds[l * 8];
        const float4 av1 = *(const float4*)&avg_lds[l * 8 + 4];
        atomicAdd(&gp[l * 8 + 0], av0.x);
        atomicAdd(&gp[l * 8 + 1], av0.y);
        atomicAdd(&gp[l * 8 + 2], av0.z);
        atomicAdd(&gp[l * 8 + 3], av0.w);
        atomicAdd(&gp[l * 8 + 4], av1.x);
        atomicAdd(&gp[l * 8 + 5], av1.y);
        atomicAdd(&gp[l * 8 + 6], av1.z);
        atomicAdd(&gp[l * 8 + 7], av1.w);
    }
}

__global__ __launch_bounds__(512) void k_final(const float* __restrict__ g_part,
                                               float* __restrict__ out) {
    __shared__ float red[8];
    const int tid = threadIdx.x;
    float sacc = 0.f;
#pragma unroll 8
    for (int i = 0; i < kSlots; ++i) sacc += g_part[(size_t)i * kStride + tid];
    const float avg = sacc * (1.0f / 65536.0f);
    const float t = avg * __logf(avg + kEpsP);
    const float sw = wsum64(t);
    if ((tid & 63) == 0) red[tid >> 6] = sw;
    __syncthreads();
    if (tid == 0) {
        float tot = 0.f;
#pragma unroll
        for (int i = 0; i < 8; ++i) tot += red[i];
        float sc0 = 0.f, sc1 = 0.f;
        for (int i = 0; i < kSlots; ++i) {
            sc0 += g_part[(size_t)i * kStride + 512];
            sc1 += g_part[(size_t)i * kStride + 513];
        }
        out[4194304] = (sc0 + sc1) * 0.125f;
        out[4194305] = __expf(-tot);
    }
}

extern "C" void kernel_launch(void* const* d_in, const int* in_sizes, int n_in,
                              void* d_out, int out_size, void* d_ws, size_t ws_size,
                              hipStream_t stream) {
    (void)in_sizes; (void)n_in; (void)out_size; (void)ws_size;
    const float* z   = (const float*)d_in[0];
    const float* kq  = (const float*)d_in[1];
    const float* cb  = (const float*)d_in[2];
    const float* gum = (const float*)d_in[3];
    float* out = (float*)d_out;

    uint16_t* cbN  = (uint16_t*)d_ws;
    uint16_t* cbNT = cbN + 32768;
    float* g_part  = (float*)(cbNT + 32768);

    (void)hipMemsetAsync(g_part, 0, kSlots * kStride * sizeof(float), stream);
    k_prep<<<128, 256, 0, stream>>>(cb, cbN, cbNT);
    k_main<<<4096, 256, 0, stream>>>(z, kq, gum, cbN, cbNT, out, g_part);
    k_final<<<1, 512, 0, stream>>>(g_part, out);
}